// Round 1
// baseline (257.625 us; speedup 1.0000x reference)
//
#include <hip/hip_runtime.h>
#include <hip/hip_bf16.h>

#define S_LEN 4096
#define NEG_INF_F (-1e30f)

typedef __attribute__((ext_vector_type(4))) float f32x4;
typedef __attribute__((ext_vector_type(8))) short s16x8;
typedef unsigned short u16;

static __device__ __forceinline__ u16 f2bf(float f) {
    unsigned u = __builtin_bit_cast(unsigned, f);
    unsigned r = u + 0x7FFFu + ((u >> 16) & 1u);
    return (u16)(r >> 16);
}
static __device__ __forceinline__ float bf2f(u16 h) {
    unsigned u = ((unsigned)h) << 16;
    return __builtin_bit_cast(float, u);
}
static __device__ __forceinline__ void split4(const float4 v, ushort4& hi, ushort4& lo) {
    hi.x = f2bf(v.x); lo.x = f2bf(v.x - bf2f(hi.x));
    hi.y = f2bf(v.y); lo.y = f2bf(v.y - bf2f(hi.y));
    hi.z = f2bf(v.z); lo.z = f2bf(v.z - bf2f(hi.z));
    hi.w = f2bf(v.w); lo.w = f2bf(v.w - bf2f(hi.w));
}

// ---------------- Kernel A: q = x@Wq^T + bq ; k = x@Wk^T + bk ----------------
// grid 1024 = 128 m-tiles x 8 n-tiles (n<4 -> q, else k). block 256 (4 waves).
__global__ __launch_bounds__(256) void proj_kernel(
    const float* __restrict__ x, const float* __restrict__ Wq,
    const float* __restrict__ bq, const float* __restrict__ Wk,
    const float* __restrict__ bk, float* __restrict__ qbuf,
    float* __restrict__ kbuf) {
    const int bid = blockIdx.x;
    const int bm = bid & 127;
    const int bn = bid >> 7;
    const int m0 = bm * 128;
    const bool isq = (bn < 4);
    const int col0 = (isq ? bn : bn - 4) * 128;
    const float* W = isq ? Wq : Wk;
    const float* bias = isq ? bq : bk;
    float* outp = isq ? qbuf : kbuf;

    __shared__ __align__(16) u16 Ah[128 * 72], Al[128 * 72];
    __shared__ __align__(16) u16 Bh[128 * 72], Bl[128 * 72];

    const int tid = threadIdx.x;
    const int lane = tid & 63;
    const int w = tid >> 6;
    const int wr = (w >> 1) * 64, wc = (w & 1) * 64;
    const int frow = lane & 15;
    const int fk = (lane >> 4) * 8;

    f32x4 acc[4][4] = {};

    for (int k0 = 0; k0 < 512; k0 += 64) {
        #pragma unroll
        for (int i = 0; i < 8; ++i) {
            int e = tid + i * 256;           // 0..2047 float4 slots
            int r = e >> 4, c4 = (e & 15) * 4;
            float4 v = *(const float4*)(x + (size_t)(m0 + r) * 512 + k0 + c4);
            ushort4 hi, lo; split4(v, hi, lo);
            *(ushort4*)&Ah[r * 72 + c4] = hi;
            *(ushort4*)&Al[r * 72 + c4] = lo;
            float4 wv = *(const float4*)(W + (size_t)(col0 + r) * 512 + k0 + c4);
            ushort4 whi, wlo; split4(wv, whi, wlo);
            *(ushort4*)&Bh[r * 72 + c4] = whi;
            *(ushort4*)&Bl[r * 72 + c4] = wlo;
        }
        __syncthreads();
        #pragma unroll
        for (int kk = 0; kk < 2; ++kk) {
            s16x8 aH[4], aL[4], bH[4], bL[4];
            #pragma unroll
            for (int mi = 0; mi < 4; ++mi) {
                int off = (wr + mi * 16 + frow) * 72 + kk * 32 + fk;
                aH[mi] = *(const s16x8*)&Ah[off];
                aL[mi] = *(const s16x8*)&Al[off];
            }
            #pragma unroll
            for (int ni = 0; ni < 4; ++ni) {
                int off = (wc + ni * 16 + frow) * 72 + kk * 32 + fk;
                bH[ni] = *(const s16x8*)&Bh[off];
                bL[ni] = *(const s16x8*)&Bl[off];
            }
            #pragma unroll
            for (int mi = 0; mi < 4; ++mi)
                #pragma unroll
                for (int ni = 0; ni < 4; ++ni) {
                    acc[mi][ni] = __builtin_amdgcn_mfma_f32_16x16x32_bf16(aH[mi], bH[ni], acc[mi][ni], 0, 0, 0);
                    acc[mi][ni] = __builtin_amdgcn_mfma_f32_16x16x32_bf16(aH[mi], bL[ni], acc[mi][ni], 0, 0, 0);
                    acc[mi][ni] = __builtin_amdgcn_mfma_f32_16x16x32_bf16(aL[mi], bH[ni], acc[mi][ni], 0, 0, 0);
                }
        }
        __syncthreads();
    }
    #pragma unroll
    for (int mi = 0; mi < 4; ++mi) {
        int rbase = m0 + wr + mi * 16 + (lane >> 4) * 4;
        #pragma unroll
        for (int ni = 0; ni < 4; ++ni) {
            int c = col0 + wc + ni * 16 + frow;
            float bv = bias[c];
            #pragma unroll
            for (int e = 0; e < 4; ++e)
                outp[(size_t)(rbase + e) * 512 + c] = acc[mi][ni][e] + bv;
        }
    }
}

// ---------------- Kernel B: banded scores + softmax -> P bf16 ----------------
// grid 256 = 4 batches x 64 row-tiles(64 rows). block 256 (4 waves, 16 rows each).
// window: jj in [0,320), j = i0-128+jj. band valid iff 1 <= jj - r <= 255.
__global__ __launch_bounds__(256) void score_kernel(
    const float* __restrict__ qbuf, const float* __restrict__ kbuf,
    u16* __restrict__ P) {
    const int bid = blockIdx.x;
    const int b = bid >> 6;
    const int it = bid & 63;
    const int i0 = it * 64;
    const int j0 = i0 - 128;
    const int mrow0 = b * S_LEN + i0;

    __shared__ __align__(16) u16 Qh[64 * 40], Ql[64 * 40];
    __shared__ __align__(16) u16 Kh[320 * 40], Kl[320 * 40];

    const int tid = threadIdx.x;
    const int lane = tid & 63;
    const int w = tid >> 6;
    const int frow = lane & 15;
    const int fk = (lane >> 4) * 8;

    f32x4 acc[20] = {};

    for (int k0 = 0; k0 < 512; k0 += 32) {
        #pragma unroll
        for (int i = 0; i < 2; ++i) {
            int e = tid + i * 256;          // 512 float4 slots (64 rows x 8)
            int r = e >> 3, c4 = (e & 7) * 4;
            float4 v = *(const float4*)(qbuf + (size_t)(mrow0 + r) * 512 + k0 + c4);
            ushort4 hi, lo; split4(v, hi, lo);
            *(ushort4*)&Qh[r * 40 + c4] = hi;
            *(ushort4*)&Ql[r * 40 + c4] = lo;
        }
        #pragma unroll
        for (int i = 0; i < 10; ++i) {
            int e = tid + i * 256;          // 2560 float4 slots (320 rows x 8)
            int r = e >> 3, c4 = (e & 7) * 4;
            int j = j0 + r;
            float4 v = make_float4(0.f, 0.f, 0.f, 0.f);
            if (j >= 0 && j < S_LEN)
                v = *(const float4*)(kbuf + (size_t)(b * S_LEN + j) * 512 + k0 + c4);
            ushort4 hi, lo; split4(v, hi, lo);
            *(ushort4*)&Kh[r * 40 + c4] = hi;
            *(ushort4*)&Kl[r * 40 + c4] = lo;
        }
        __syncthreads();
        s16x8 aH = *(const s16x8*)&Qh[(w * 16 + frow) * 40 + fk];
        s16x8 aL = *(const s16x8*)&Ql[(w * 16 + frow) * 40 + fk];
        #pragma unroll
        for (int t = 0; t < 20; ++t) {
            s16x8 bH = *(const s16x8*)&Kh[(t * 16 + frow) * 40 + fk];
            s16x8 bL = *(const s16x8*)&Kl[(t * 16 + frow) * 40 + fk];
            acc[t] = __builtin_amdgcn_mfma_f32_16x16x32_bf16(aH, bH, acc[t], 0, 0, 0);
            acc[t] = __builtin_amdgcn_mfma_f32_16x16x32_bf16(aH, bL, acc[t], 0, 0, 0);
            acc[t] = __builtin_amdgcn_mfma_f32_16x16x32_bf16(aL, bH, acc[t], 0, 0, 0);
        }
        __syncthreads();
    }

    const int rloc = w * 16 + (lane >> 4) * 4;
    #pragma unroll
    for (int e = 0; e < 4; ++e) {
        const int r = rloc + e;
        float mx = NEG_INF_F;
        #pragma unroll
        for (int t = 0; t < 20; ++t) {
            int jj = t * 16 + frow;
            int dj = jj - r;
            int j = j0 + jj;
            bool valid = (dj >= 1) && (dj <= 255) && (j >= 0) && (j < S_LEN);
            if (valid) mx = fmaxf(mx, acc[t][e]);
        }
        #pragma unroll
        for (int d = 1; d < 16; d <<= 1) mx = fmaxf(mx, __shfl_xor(mx, d));
        float p[20];
        float sum = 0.f;
        #pragma unroll
        for (int t = 0; t < 20; ++t) {
            int jj = t * 16 + frow;
            int dj = jj - r;
            int j = j0 + jj;
            bool valid = (dj >= 1) && (dj <= 255) && (j >= 0) && (j < S_LEN);
            p[t] = valid ? __expf(acc[t][e] - mx) : 0.f;
            sum += p[t];
        }
        #pragma unroll
        for (int d = 1; d < 16; d <<= 1) sum += __shfl_xor(sum, d);
        const float inv = 1.f / sum;
        const size_t rowoff = (size_t)(mrow0 + r) * 320;
        #pragma unroll
        for (int t = 0; t < 20; ++t)
            P[rowoff + t * 16 + frow] = f2bf(p[t] * inv);
    }
}

// ---------------- Kernel C: out = P @ x_window ----------------
// grid 1024 = 4 b x 64 row-tiles x 4 d-blocks(128). block 256 (4 waves, 16 rows each).
__global__ __launch_bounds__(256) void pv_kernel(
    const u16* __restrict__ P, const float* __restrict__ x,
    float* __restrict__ out) {
    const int bid = blockIdx.x;
    const int dblk = bid & 3;
    const int it = (bid >> 2) & 63;
    const int b = bid >> 8;
    const int i0 = it * 64;
    const int j0 = i0 - 128;
    const int d0 = dblk * 128;
    const int mrow0 = b * S_LEN + i0;

    __shared__ __align__(16) u16 Ph[64 * 40];
    __shared__ __align__(16) u16 XT[128 * 40];

    const int tid = threadIdx.x;
    const int lane = tid & 63;
    const int w = tid >> 6;
    const int frow = lane & 15;
    const int fk = (lane >> 4) * 8;

    f32x4 acc[8] = {};

    for (int k0 = 0; k0 < 320; k0 += 32) {
        #pragma unroll
        for (int i = 0; i < 2; ++i) {
            int e = tid + i * 256;          // 512 ushort4 slots (64 rows x 8)
            int r = e >> 3, c4 = (e & 7) * 4;
            ushort4 v = *(const ushort4*)(P + (size_t)(mrow0 + r) * 320 + k0 + c4);
            *(ushort4*)&Ph[r * 40 + c4] = v;
        }
        #pragma unroll
        for (int i = 0; i < 4; ++i) {
            int e = tid + i * 256;          // 1024 float4 slots (32 k-rows x 32)
            int k = e >> 5, c4 = (e & 31) * 4;
            int j = j0 + k0 + k;
            j = min(max(j, 0), S_LEN - 1);  // P==0 there, value irrelevant
            float4 v = *(const float4*)(x + (size_t)(b * S_LEN + j) * 512 + d0 + c4);
            XT[(c4 + 0) * 40 + k] = f2bf(v.x);
            XT[(c4 + 1) * 40 + k] = f2bf(v.y);
            XT[(c4 + 2) * 40 + k] = f2bf(v.z);
            XT[(c4 + 3) * 40 + k] = f2bf(v.w);
        }
        __syncthreads();
        s16x8 a = *(const s16x8*)&Ph[(w * 16 + frow) * 40 + fk];
        #pragma unroll
        for (int ni = 0; ni < 8; ++ni) {
            s16x8 bf = *(const s16x8*)&XT[(ni * 16 + frow) * 40 + fk];
            acc[ni] = __builtin_amdgcn_mfma_f32_16x16x32_bf16(a, bf, acc[ni], 0, 0, 0);
        }
        __syncthreads();
    }
    #pragma unroll
    for (int ni = 0; ni < 8; ++ni) {
        int c = d0 + ni * 16 + frow;
        #pragma unroll
        for (int e = 0; e < 4; ++e) {
            int r = i0 + w * 16 + (lane >> 4) * 4 + e;
            out[(size_t)(b * S_LEN + r) * 512 + c] = acc[ni][e];
        }
    }
}

extern "C" void kernel_launch(void* const* d_in, const int* in_sizes, int n_in,
                              void* d_out, int out_size, void* d_ws, size_t ws_size,
                              hipStream_t stream) {
    const float* x  = (const float*)d_in[0];
    const float* Wq = (const float*)d_in[1];
    const float* bq = (const float*)d_in[2];
    const float* Wk = (const float*)d_in[3];
    const float* bk = (const float*)d_in[4];
    float* out = (float*)d_out;

    float* qbuf = (float*)d_ws;
    float* kbuf = qbuf + (size_t)16384 * 512;
    u16*   Pbuf = (u16*)(kbuf + (size_t)16384 * 512);

    hipLaunchKernelGGL(proj_kernel, dim3(1024), dim3(256), 0, stream,
                       x, Wq, bq, Wk, bk, qbuf, kbuf);
    hipLaunchKernelGGL(score_kernel, dim3(256), dim3(256), 0, stream,
                       qbuf, kbuf, Pbuf);
    hipLaunchKernelGGL(pv_kernel, dim3(1024), dim3(256), 0, stream,
                       Pbuf, x, out);
}

// Round 2
// 187.379 us; speedup vs baseline: 1.3749x; 1.3749x over previous
//
#include <hip/hip_runtime.h>
#include <hip/hip_bf16.h>

#define S_LEN 4096
#define NEG_INF_F (-1e30f)

typedef __attribute__((ext_vector_type(4))) float f32x4;
typedef __attribute__((ext_vector_type(8))) short s16x8;
typedef unsigned short u16;

static __device__ __forceinline__ u16 f2bf(float f) {
    unsigned u = __builtin_bit_cast(unsigned, f);
    unsigned r = u + 0x7FFFu + ((u >> 16) & 1u);
    return (u16)(r >> 16);
}
static __device__ __forceinline__ float bf2f(u16 h) {
    unsigned u = ((unsigned)h) << 16;
    return __builtin_bit_cast(float, u);
}
static __device__ __forceinline__ void split4(const float4 v, ushort4& hi, ushort4& lo) {
    hi.x = f2bf(v.x); lo.x = f2bf(v.x - bf2f(hi.x));
    hi.y = f2bf(v.y); lo.y = f2bf(v.y - bf2f(hi.y));
    hi.z = f2bf(v.z); lo.z = f2bf(v.z - bf2f(hi.z));
    hi.w = f2bf(v.w); lo.w = f2bf(v.w - bf2f(hi.w));
}

static __device__ __forceinline__ void gl_lds16(const void* g, void* l) {
    __builtin_amdgcn_global_load_lds(
        (const __attribute__((address_space(1))) void*)g,
        (__attribute__((address_space(3))) void*)l, 16, 0, 0);
}

// ---------------- K0: split x -> xh, xl (bf16 hi/lo) ----------------
__global__ __launch_bounds__(256) void split_kernel(
    const float* __restrict__ x, u16* __restrict__ xh, u16* __restrict__ xl) {
    size_t base = (size_t)blockIdx.x * 256 + threadIdx.x;
    #pragma unroll
    for (int i = 0; i < 4; ++i) {
        size_t idx = base + (size_t)i * 524288;   // 2048*256 blocksz-threads
        float4 v = ((const float4*)x)[idx];
        ushort4 hi, lo; split4(v, hi, lo);
        ((ushort4*)xh)[idx] = hi;
        ((ushort4*)xl)[idx] = lo;
    }
}

// ---------------- K1: Mt = Wk^T @ Wq  (Mt[d2][d1] = sum_h Wk[h][d2]*Wq[h][d1]) ----
// grid 64 = 8x8 tiles of 64x64. block 256 (4 waves). 3-pass split MFMA.
__global__ __launch_bounds__(256) void mt_kernel(
    const float* __restrict__ Wk, const float* __restrict__ Wq,
    u16* __restrict__ Mth, u16* __restrict__ Mtl) {
    const int bm = blockIdx.x & 7, bn = blockIdx.x >> 3;
    const int m0 = bm * 64, n0 = bn * 64;
    __shared__ __align__(16) u16 Ath[64 * 72], Atl[64 * 72];
    __shared__ __align__(16) u16 Bth[64 * 72], Btl[64 * 72];
    const int tid = threadIdx.x, lane = tid & 63, w = tid >> 6;
    const int frow = lane & 15, fk = (lane >> 4) * 8;
    f32x4 acc[4] = {};

    for (int h0 = 0; h0 < 512; h0 += 64) {
        #pragma unroll
        for (int i = 0; i < 4; ++i) {
            int idx = i * 256 + tid;
            int h = idx >> 4, c4 = (idx & 15) * 4;
            float4 a = *(const float4*)(Wk + (size_t)(h0 + h) * 512 + m0 + c4);
            ushort4 ahi, alo; split4(a, ahi, alo);
            Ath[(c4 + 0) * 72 + h] = ahi.x; Atl[(c4 + 0) * 72 + h] = alo.x;
            Ath[(c4 + 1) * 72 + h] = ahi.y; Atl[(c4 + 1) * 72 + h] = alo.y;
            Ath[(c4 + 2) * 72 + h] = ahi.z; Atl[(c4 + 2) * 72 + h] = alo.z;
            Ath[(c4 + 3) * 72 + h] = ahi.w; Atl[(c4 + 3) * 72 + h] = alo.w;
            float4 b = *(const float4*)(Wq + (size_t)(h0 + h) * 512 + n0 + c4);
            ushort4 bhi, blo; split4(b, bhi, blo);
            Bth[(c4 + 0) * 72 + h] = bhi.x; Btl[(c4 + 0) * 72 + h] = blo.x;
            Bth[(c4 + 1) * 72 + h] = bhi.y; Btl[(c4 + 1) * 72 + h] = blo.y;
            Bth[(c4 + 2) * 72 + h] = bhi.z; Btl[(c4 + 2) * 72 + h] = blo.z;
            Bth[(c4 + 3) * 72 + h] = bhi.w; Btl[(c4 + 3) * 72 + h] = blo.w;
        }
        __syncthreads();
        #pragma unroll
        for (int kk = 0; kk < 2; ++kk) {
            s16x8 aH = *(const s16x8*)&Ath[(w * 16 + frow) * 72 + kk * 32 + fk];
            s16x8 aL = *(const s16x8*)&Atl[(w * 16 + frow) * 72 + kk * 32 + fk];
            #pragma unroll
            for (int ni = 0; ni < 4; ++ni) {
                s16x8 bH = *(const s16x8*)&Bth[(ni * 16 + frow) * 72 + kk * 32 + fk];
                s16x8 bL = *(const s16x8*)&Btl[(ni * 16 + frow) * 72 + kk * 32 + fk];
                acc[ni] = __builtin_amdgcn_mfma_f32_16x16x32_bf16(aH, bH, acc[ni], 0, 0, 0);
                acc[ni] = __builtin_amdgcn_mfma_f32_16x16x32_bf16(aH, bL, acc[ni], 0, 0, 0);
                acc[ni] = __builtin_amdgcn_mfma_f32_16x16x32_bf16(aL, bH, acc[ni], 0, 0, 0);
            }
        }
        __syncthreads();
    }
    #pragma unroll
    for (int ni = 0; ni < 4; ++ni) {
        int d1 = n0 + ni * 16 + frow;
        #pragma unroll
        for (int e = 0; e < 4; ++e) {
            int d2 = m0 + w * 16 + (lane >> 4) * 4 + e;
            float v = acc[ni][e];
            u16 hi = f2bf(v);
            Mth[(size_t)d2 * 512 + d1] = hi;
            Mtl[(size_t)d2 * 512 + d1] = f2bf(v - bf2f(hi));
        }
    }
}

// ---------------- K2: u = Wk^T @ bq ----------------
__global__ __launch_bounds__(256) void u_kernel(
    const float* __restrict__ Wk, const float* __restrict__ bq,
    float* __restrict__ u) {
    __shared__ float red[4][64];
    const int tid = threadIdx.x, c = tid & 63, hg = tid >> 6;
    const int d2 = blockIdx.x * 64 + c;
    float acc = 0.f;
    for (int h = hg; h < 512; h += 4) acc += Wk[(size_t)h * 512 + d2] * bq[h];
    red[hg][c] = acc;
    __syncthreads();
    if (hg == 0) u[d2] = red[0][c] + red[1][c] + red[2][c] + red[3][c];
}

// ---------------- K3: z = x @ Mt^T + u, output split bf16 ----------------
// grid 512 = 128 m-tiles x 4 n-tiles. block 256 (4 waves). 3-pass.
__global__ __launch_bounds__(256) void z_kernel(
    const u16* __restrict__ xh, const u16* __restrict__ xl,
    const u16* __restrict__ Mth, const u16* __restrict__ Mtl,
    const float* __restrict__ u, u16* __restrict__ zh, u16* __restrict__ zl) {
    const int bm = blockIdx.x >> 2, bn = blockIdx.x & 3;
    const int m0 = bm * 128, n0 = bn * 128;
    __shared__ __align__(16) u16 Ah[128 * 64], Al[128 * 64];
    __shared__ __align__(16) u16 Bh[128 * 64], Bl[128 * 64];
    const int tid = threadIdx.x, lane = tid & 63, w = tid >> 6;
    const int wr = (w >> 1) * 64, wc = (w & 1) * 64;
    const int frow = lane & 15, fk = (lane >> 4) * 8;
    f32x4 acc[4][4] = {};

    for (int k0 = 0; k0 < 512; k0 += 64) {
        #pragma unroll
        for (int i = 0; i < 4; ++i) {
            int idx = i * 256 + tid;           // 1024 chunks of 16B per array
            int r = idx >> 3, c8 = idx & 7;
            gl_lds16(xh + (size_t)(m0 + r) * 512 + k0 + c8 * 8, &Ah[idx * 8]);
            gl_lds16(xl + (size_t)(m0 + r) * 512 + k0 + c8 * 8, &Al[idx * 8]);
            gl_lds16(Mth + (size_t)(n0 + r) * 512 + k0 + c8 * 8, &Bh[idx * 8]);
            gl_lds16(Mtl + (size_t)(n0 + r) * 512 + k0 + c8 * 8, &Bl[idx * 8]);
        }
        __syncthreads();
        #pragma unroll
        for (int kk = 0; kk < 2; ++kk) {
            s16x8 aH[4], aL[4], bH[4], bL[4];
            #pragma unroll
            for (int mi = 0; mi < 4; ++mi) {
                int off = (wr + mi * 16 + frow) * 64 + kk * 32 + fk;
                aH[mi] = *(const s16x8*)&Ah[off];
                aL[mi] = *(const s16x8*)&Al[off];
            }
            #pragma unroll
            for (int ni = 0; ni < 4; ++ni) {
                int off = (wc + ni * 16 + frow) * 64 + kk * 32 + fk;
                bH[ni] = *(const s16x8*)&Bh[off];
                bL[ni] = *(const s16x8*)&Bl[off];
            }
            #pragma unroll
            for (int mi = 0; mi < 4; ++mi)
                #pragma unroll
                for (int ni = 0; ni < 4; ++ni) {
                    acc[mi][ni] = __builtin_amdgcn_mfma_f32_16x16x32_bf16(aH[mi], bH[ni], acc[mi][ni], 0, 0, 0);
                    acc[mi][ni] = __builtin_amdgcn_mfma_f32_16x16x32_bf16(aH[mi], bL[ni], acc[mi][ni], 0, 0, 0);
                    acc[mi][ni] = __builtin_amdgcn_mfma_f32_16x16x32_bf16(aL[mi], bH[ni], acc[mi][ni], 0, 0, 0);
                }
        }
        __syncthreads();
    }
    #pragma unroll
    for (int ni = 0; ni < 4; ++ni) {
        int col = n0 + wc + ni * 16 + frow;
        float uv = u[col];
        #pragma unroll
        for (int mi = 0; mi < 4; ++mi) {
            int rbase = m0 + wr + mi * 16 + (lane >> 4) * 4;
            #pragma unroll
            for (int e = 0; e < 4; ++e) {
                float v = acc[mi][ni][e] + uv;
                u16 hi = f2bf(v);
                zh[(size_t)(rbase + e) * 512 + col] = hi;
                zl[(size_t)(rbase + e) * 512 + col] = f2bf(v - bf2f(hi));
            }
        }
    }
}

// ---------------- K4: banded scores S = z @ x^T, softmax -> P bf16 ----------------
// grid 256 = 4 b x 64 row-tiles(64). block 512 (8 waves): 4 row-groups x 2 window-halves.
// window jj in [0,320), j = i0-128+jj; valid iff 1<=jj-r<=255 and 0<=j<S.
// group g rows [g*16, g*16+16): valid tiles t in [g, g+16] (17 of 20).
__global__ __launch_bounds__(512) void score_kernel(
    const u16* __restrict__ zh, const u16* __restrict__ zl,
    const u16* __restrict__ xh, const u16* __restrict__ xl,
    u16* __restrict__ P) {
    const int bid = blockIdx.x;
    const int b = bid >> 6, it = bid & 63;
    const int i0 = it * 64, j0 = i0 - 128;
    const int mrow0 = b * S_LEN + i0;
    __shared__ __align__(16) u16 Qh[64 * 64], Ql[64 * 64];
    __shared__ __align__(16) u16 Kh[320 * 64], Kl[320 * 64];
    __shared__ float smax[64][2], ssum[64][2];

    const int tid = threadIdx.x, lane = tid & 63, w = tid >> 6;
    const int g = w >> 1, half = w & 1;
    const int frow = lane & 15, fk = (lane >> 4) * 8;
    const int tstart = g + (half ? 9 : 0);
    const int nt = half ? 8 : 9;
    const bool hiHalf = (tid >= 256);

    f32x4 acc[9] = {};

    for (int k0 = 0; k0 < 512; k0 += 64) {
        {   // Q arrays: 512 chunks each; waves 0-3 stage Qh, 4-7 stage Ql
            int idx = tid & 255;  // 256 chunks... (64 rows x 8)/2 handled below
            // 64 rows * 8 chunks/row = 512 chunks per array; use full tid for one array
            int idq = tid;        // 0..511 -> whole Qh by low waves? need both arrays:
            (void)idx; (void)idq;
        }
        // Qh+Ql: 1024 chunks total: thread stages 2 (one per array)
        {
            int idx = tid;                       // 512 chunks: r = idx>>3, c8 = idx&7
            int r = idx >> 3, c8 = idx & 7;
            gl_lds16(zh + (size_t)(mrow0 + r) * 512 + k0 + c8 * 8, &Qh[idx * 8]);
            gl_lds16(zl + (size_t)(mrow0 + r) * 512 + k0 + c8 * 8, &Ql[idx * 8]);
        }
        // K arrays: 2560 chunks each (320 rows x 8)
        #pragma unroll
        for (int i = 0; i < 5; ++i) {
            int idx = i * 512 + tid;
            int r = idx >> 3, c8 = idx & 7;
            int j = j0 + r;
            int jc = min(max(j, 0), S_LEN - 1);
            gl_lds16(xh + (size_t)(b * S_LEN + jc) * 512 + k0 + c8 * 8, &Kh[idx * 8]);
            gl_lds16(xl + (size_t)(b * S_LEN + jc) * 512 + k0 + c8 * 8, &Kl[idx * 8]);
        }
        __syncthreads();
        #pragma unroll
        for (int kk = 0; kk < 2; ++kk) {
            s16x8 aH = *(const s16x8*)&Qh[(g * 16 + frow) * 64 + kk * 32 + fk];
            s16x8 aL = *(const s16x8*)&Ql[(g * 16 + frow) * 64 + kk * 32 + fk];
            #pragma unroll
            for (int tt = 0; tt < 9; ++tt) {
                if (tt < nt) {
                    int t = tstart + tt;
                    s16x8 bH = *(const s16x8*)&Kh[(t * 16 + frow) * 64 + kk * 32 + fk];
                    s16x8 bL = *(const s16x8*)&Kl[(t * 16 + frow) * 64 + kk * 32 + fk];
                    acc[tt] = __builtin_amdgcn_mfma_f32_16x16x32_bf16(aH, bH, acc[tt], 0, 0, 0);
                    acc[tt] = __builtin_amdgcn_mfma_f32_16x16x32_bf16(aH, bL, acc[tt], 0, 0, 0);
                    acc[tt] = __builtin_amdgcn_mfma_f32_16x16x32_bf16(aL, bH, acc[tt], 0, 0, 0);
                }
            }
        }
        __syncthreads();
    }
    (void)hiHalf;

    const int rq = (lane >> 4) * 4;
    // phase 1: per-half row max
    float mxh[4];
    #pragma unroll
    for (int e = 0; e < 4; ++e) {
        int r = g * 16 + rq + e;
        float m = NEG_INF_F;
        #pragma unroll
        for (int tt = 0; tt < 9; ++tt) {
            if (tt < nt) {
                int jj = (tstart + tt) * 16 + frow;
                int dj = jj - r, j = j0 + jj;
                if (dj >= 1 && dj <= 255 && j >= 0 && j < S_LEN) m = fmaxf(m, acc[tt][e]);
            }
        }
        #pragma unroll
        for (int d = 1; d < 16; d <<= 1) m = fmaxf(m, __shfl_xor(m, d));
        mxh[e] = m;
    }
    if (frow == 0) {
        #pragma unroll
        for (int e = 0; e < 4; ++e) smax[g * 16 + rq + e][half] = mxh[e];
    }
    __syncthreads();
    // phase 2: exp + per-half sum
    float p[9][4];
    float sh[4];
    #pragma unroll
    for (int e = 0; e < 4; ++e) {
        int r = g * 16 + rq + e;
        float mx = fmaxf(smax[r][0], smax[r][1]);
        float s = 0.f;
        #pragma unroll
        for (int tt = 0; tt < 9; ++tt) {
            float pv = 0.f;
            if (tt < nt) {
                int jj = (tstart + tt) * 16 + frow;
                int dj = jj - r, j = j0 + jj;
                bool valid = (dj >= 1 && dj <= 255 && j >= 0 && j < S_LEN);
                pv = valid ? __expf(acc[tt][e] - mx) : 0.f;
            }
            p[tt][e] = pv;
            s += pv;
        }
        #pragma unroll
        for (int d = 1; d < 16; d <<= 1) s += __shfl_xor(s, d);
        sh[e] = s;
    }
    if (frow == 0) {
        #pragma unroll
        for (int e = 0; e < 4; ++e) ssum[g * 16 + rq + e][half] = sh[e];
    }
    __syncthreads();
    float invv[4];
    #pragma unroll
    for (int e = 0; e < 4; ++e) {
        int r = g * 16 + rq + e;
        invv[e] = 1.f / (ssum[r][0] + ssum[r][1]);
    }
    // phase 3: write P (own tiles + zero-fill so all 20 tiles are defined)
    #pragma unroll
    for (int tt = 0; tt < 9; ++tt) {
        if (tt < nt) {
            int t = tstart + tt;
            #pragma unroll
            for (int e = 0; e < 4; ++e) {
                int r = g * 16 + rq + e;
                P[(size_t)(mrow0 + r) * 320 + t * 16 + frow] = f2bf(p[tt][e] * invv[e]);
            }
        }
    }
    if (half == 0) {
        for (int t = 0; t < g; ++t)
            #pragma unroll
            for (int e = 0; e < 4; ++e)
                P[(size_t)(mrow0 + g * 16 + rq + e) * 320 + t * 16 + frow] = 0;
    } else {
        for (int t = g + 17; t < 20; ++t)
            #pragma unroll
            for (int e = 0; e < 4; ++e)
                P[(size_t)(mrow0 + g * 16 + rq + e) * 320 + t * 16 + frow] = 0;
    }
}

// ---------------- K5: out = P @ x_window ----------------
// grid 1024 = 4 b x 64 it x 4 dblk. block 256 (4 waves of 16 rows).
__global__ __launch_bounds__(256) void pv_kernel(
    const u16* __restrict__ P, const u16* __restrict__ xh,
    float* __restrict__ out) {
    const int bid = blockIdx.x;
    const int dblk = bid & 3, it = (bid >> 2) & 63, b = bid >> 8;
    const int i0 = it * 64, j0 = i0 - 128, d0 = dblk * 128;
    const int mrow0 = b * S_LEN + i0;
    __shared__ __align__(16) u16 Ph[64 * 32];
    __shared__ __align__(16) u16 XT[128 * 40];
    const int tid = threadIdx.x, lane = tid & 63, g = tid >> 6;
    const int frow = lane & 15, fk = (lane >> 4) * 8;
    f32x4 acc[8] = {};

    for (int k0 = 0; k0 < 320; k0 += 32) {
        {   // P tile: 256 chunks
            int idx = tid;
            int r = idx >> 2, c8 = idx & 3;
            gl_lds16(P + (size_t)(mrow0 + r) * 320 + k0 + c8 * 8, &Ph[idx * 8]);
        }
        #pragma unroll
        for (int i = 0; i < 2; ++i) {   // x transpose: 32 j-rows x 128 cols
            int idx = i * 256 + tid;
            int jrow = idx >> 4, c8 = (idx & 15) * 8;
            int j = j0 + k0 + jrow;
            int jc = min(max(j, 0), S_LEN - 1);
            s16x8 v = *(const s16x8*)&xh[(size_t)(b * S_LEN + jc) * 512 + d0 + c8];
            #pragma unroll
            for (int t = 0; t < 8; ++t) XT[(c8 + t) * 40 + jrow] = (u16)v[t];
        }
        __syncthreads();
        // wave g valid k range [g*16+1, g*16+270]
        if (k0 + 31 >= g * 16 + 1 && k0 <= g * 16 + 270) {
            s16x8 a = *(const s16x8*)&Ph[(g * 16 + frow) * 32 + fk];
            #pragma unroll
            for (int ni = 0; ni < 8; ++ni) {
                s16x8 bf = *(const s16x8*)&XT[(ni * 16 + frow) * 40 + fk];
                acc[ni] = __builtin_amdgcn_mfma_f32_16x16x32_bf16(a, bf, acc[ni], 0, 0, 0);
            }
        }
        __syncthreads();
    }
    #pragma unroll
    for (int ni = 0; ni < 8; ++ni) {
        int c = d0 + ni * 16 + frow;
        #pragma unroll
        for (int e = 0; e < 4; ++e) {
            int r = mrow0 + g * 16 + (lane >> 4) * 4 + e;
            out[(size_t)r * 512 + c] = acc[ni][e];
        }
    }
}

extern "C" void kernel_launch(void* const* d_in, const int* in_sizes, int n_in,
                              void* d_out, int out_size, void* d_ws, size_t ws_size,
                              hipStream_t stream) {
    const float* x  = (const float*)d_in[0];
    const float* Wq = (const float*)d_in[1];
    const float* bq = (const float*)d_in[2];
    const float* Wk = (const float*)d_in[3];
    const float* bk = (const float*)d_in[4];
    (void)bk;
    float* out = (float*)d_out;

    u16* xh  = (u16*)d_ws;
    u16* xl  = xh + (size_t)8388608;
    u16* zh  = xl + (size_t)8388608;
    u16* zl  = zh + (size_t)8388608;
    u16* Mth = zl + (size_t)8388608;
    u16* Mtl = Mth + (size_t)262144;
    u16* Pb  = Mtl + (size_t)262144;
    float* uv = (float*)(Pb + (size_t)16384 * 320);

    hipLaunchKernelGGL(split_kernel, dim3(2048), dim3(256), 0, stream, x, xh, xl);
    hipLaunchKernelGGL(mt_kernel, dim3(64), dim3(256), 0, stream, Wk, Wq, Mth, Mtl);
    hipLaunchKernelGGL(u_kernel, dim3(8), dim3(256), 0, stream, Wk, bq, uv);
    hipLaunchKernelGGL(z_kernel, dim3(512), dim3(256), 0, stream,
                       xh, xl, Mth, Mtl, uv, zh, zl);
    hipLaunchKernelGGL(score_kernel, dim3(256), dim3(512), 0, stream,
                       zh, zl, xh, xl, Pb);
    hipLaunchKernelGGL(pv_kernel, dim3(1024), dim3(256), 0, stream, Pb, xh, out);
}

// Round 3
// 162.477 us; speedup vs baseline: 1.5856x; 1.1533x over previous
//
#include <hip/hip_runtime.h>
#include <hip/hip_bf16.h>

#define S_LEN 4096
#define NEG_INF_F (-1e30f)

typedef __attribute__((ext_vector_type(4))) float f32x4;
typedef __attribute__((ext_vector_type(8))) short s16x8;
typedef unsigned short u16;

static __device__ __forceinline__ u16 f2bf(float f) {
    unsigned u = __builtin_bit_cast(unsigned, f);
    unsigned r = u + 0x7FFFu + ((u >> 16) & 1u);
    return (u16)(r >> 16);
}
static __device__ __forceinline__ float bf2f(u16 h) {
    unsigned u = ((unsigned)h) << 16;
    return __builtin_bit_cast(float, u);
}
static __device__ __forceinline__ void split4(const float4 v, ushort4& hi, ushort4& lo) {
    hi.x = f2bf(v.x); lo.x = f2bf(v.x - bf2f(hi.x));
    hi.y = f2bf(v.y); lo.y = f2bf(v.y - bf2f(hi.y));
    hi.z = f2bf(v.z); lo.z = f2bf(v.z - bf2f(hi.z));
    hi.w = f2bf(v.w); lo.w = f2bf(v.w - bf2f(hi.w));
}
static __device__ __forceinline__ void gl_lds16(const void* g, void* l) {
    __builtin_amdgcn_global_load_lds(
        (const __attribute__((address_space(1))) void*)g,
        (__attribute__((address_space(3))) void*)l, 16, 0, 0);
}
// swizzled u16 offset within a [rows][64 u16] LDS tile
static __device__ __forceinline__ int swz(int row, int col_u16) {
    return row * 64 + (col_u16 ^ ((row & 7) << 3));
}

// ---------------- K0: split x -> xh, xl (bf16 hi/lo) ----------------
__global__ __launch_bounds__(256) void split_kernel(
    const float* __restrict__ x, u16* __restrict__ xh, u16* __restrict__ xl) {
    size_t base = (size_t)blockIdx.x * 256 + threadIdx.x;
    #pragma unroll
    for (int i = 0; i < 4; ++i) {
        size_t idx = base + (size_t)i * 524288;
        float4 v = ((const float4*)x)[idx];
        ushort4 hi, lo; split4(v, hi, lo);
        ((ushort4*)xh)[idx] = hi;
        ((ushort4*)xl)[idx] = lo;
    }
}

// ---------------- K1: xT[b][d][s] = xh[b][s][d] ----------------
// grid 2048 = 4b x 64 s-tiles x 8 d-tiles. block 256.
__global__ __launch_bounds__(256) void xt_kernel(
    const u16* __restrict__ xh, u16* __restrict__ xT) {
    const int bid = blockIdx.x;
    const int dt = bid & 7, st = (bid >> 3) & 63, b = bid >> 9;
    const int s0 = st * 64, d0 = dt * 64;
    __shared__ u16 T[64][72];
    const int tid = threadIdx.x;
    #pragma unroll
    for (int i = 0; i < 2; ++i) {
        int idx = i * 256 + tid;
        int r = idx >> 3, c8 = idx & 7;
        s16x8 v = *(const s16x8*)&xh[(size_t)(b * S_LEN + s0 + r) * 512 + d0 + c8 * 8];
        *(s16x8*)&T[r][c8 * 8] = v;
    }
    __syncthreads();
    #pragma unroll
    for (int i = 0; i < 2; ++i) {
        int idx = i * 256 + tid;
        int dr = idx >> 3, sc = idx & 7;
        s16x8 v;
        #pragma unroll
        for (int t = 0; t < 8; ++t) v[t] = (short)T[sc * 8 + t][dr];
        *(s16x8*)&xT[(size_t)(b * 512 + d0 + dr) * S_LEN + s0 + sc * 8] = v;
    }
}

// ---------------- K2: Mt = Wk^T @ Wq ----------------
__global__ __launch_bounds__(256) void mt_kernel(
    const float* __restrict__ Wk, const float* __restrict__ Wq,
    u16* __restrict__ Mth, u16* __restrict__ Mtl) {
    const int bm = blockIdx.x & 7, bn = blockIdx.x >> 3;
    const int m0 = bm * 64, n0 = bn * 64;
    __shared__ __align__(16) u16 Ath[64 * 72], Atl[64 * 72];
    __shared__ __align__(16) u16 Bth[64 * 72], Btl[64 * 72];
    const int tid = threadIdx.x, lane = tid & 63, w = tid >> 6;
    const int frow = lane & 15, fk = (lane >> 4) * 8;
    f32x4 acc[4] = {};

    for (int h0 = 0; h0 < 512; h0 += 64) {
        #pragma unroll
        for (int i = 0; i < 4; ++i) {
            int idx = i * 256 + tid;
            int h = idx >> 4, c4 = (idx & 15) * 4;
            float4 a = *(const float4*)(Wk + (size_t)(h0 + h) * 512 + m0 + c4);
            ushort4 ahi, alo; split4(a, ahi, alo);
            Ath[(c4 + 0) * 72 + h] = ahi.x; Atl[(c4 + 0) * 72 + h] = alo.x;
            Ath[(c4 + 1) * 72 + h] = ahi.y; Atl[(c4 + 1) * 72 + h] = alo.y;
            Ath[(c4 + 2) * 72 + h] = ahi.z; Atl[(c4 + 2) * 72 + h] = alo.z;
            Ath[(c4 + 3) * 72 + h] = ahi.w; Atl[(c4 + 3) * 72 + h] = alo.w;
            float4 b = *(const float4*)(Wq + (size_t)(h0 + h) * 512 + n0 + c4);
            ushort4 bhi, blo; split4(b, bhi, blo);
            Bth[(c4 + 0) * 72 + h] = bhi.x; Btl[(c4 + 0) * 72 + h] = blo.x;
            Bth[(c4 + 1) * 72 + h] = bhi.y; Btl[(c4 + 1) * 72 + h] = blo.y;
            Bth[(c4 + 2) * 72 + h] = bhi.z; Btl[(c4 + 2) * 72 + h] = blo.z;
            Bth[(c4 + 3) * 72 + h] = bhi.w; Btl[(c4 + 3) * 72 + h] = blo.w;
        }
        __syncthreads();
        #pragma unroll
        for (int kk = 0; kk < 2; ++kk) {
            s16x8 aH = *(const s16x8*)&Ath[(w * 16 + frow) * 72 + kk * 32 + fk];
            s16x8 aL = *(const s16x8*)&Atl[(w * 16 + frow) * 72 + kk * 32 + fk];
            #pragma unroll
            for (int ni = 0; ni < 4; ++ni) {
                s16x8 bH = *(const s16x8*)&Bth[(ni * 16 + frow) * 72 + kk * 32 + fk];
                s16x8 bL = *(const s16x8*)&Btl[(ni * 16 + frow) * 72 + kk * 32 + fk];
                acc[ni] = __builtin_amdgcn_mfma_f32_16x16x32_bf16(aH, bH, acc[ni], 0, 0, 0);
                acc[ni] = __builtin_amdgcn_mfma_f32_16x16x32_bf16(aH, bL, acc[ni], 0, 0, 0);
                acc[ni] = __builtin_amdgcn_mfma_f32_16x16x32_bf16(aL, bH, acc[ni], 0, 0, 0);
            }
        }
        __syncthreads();
    }
    #pragma unroll
    for (int ni = 0; ni < 4; ++ni) {
        int d1 = n0 + ni * 16 + frow;
        #pragma unroll
        for (int e = 0; e < 4; ++e) {
            int d2 = m0 + w * 16 + (lane >> 4) * 4 + e;
            float v = acc[ni][e];
            u16 hi = f2bf(v);
            Mth[(size_t)d2 * 512 + d1] = hi;
            Mtl[(size_t)d2 * 512 + d1] = f2bf(v - bf2f(hi));
        }
    }
}

// ---------------- K3: u = Wk^T @ bq ----------------
__global__ __launch_bounds__(256) void u_kernel(
    const float* __restrict__ Wk, const float* __restrict__ bq,
    float* __restrict__ u) {
    __shared__ float red[4][64];
    const int tid = threadIdx.x, c = tid & 63, hg = tid >> 6;
    const int d2 = blockIdx.x * 64 + c;
    float acc = 0.f;
    for (int h = hg; h < 512; h += 4) acc += Wk[(size_t)h * 512 + d2] * bq[h];
    red[hg][c] = acc;
    __syncthreads();
    if (hg == 0) u[d2] = red[0][c] + red[1][c] + red[2][c] + red[3][c];
}

// ---------------- K4: z = x @ Mt^T + u, output split bf16 ----------------
// grid 512 = 128 m-tiles x 4 n-tiles. block 512 (8 waves: 2 rg x 4 cg).
__global__ __launch_bounds__(512) void z_kernel(
    const u16* __restrict__ xh, const u16* __restrict__ xl,
    const u16* __restrict__ Mth, const u16* __restrict__ Mtl,
    const float* __restrict__ u, u16* __restrict__ zh, u16* __restrict__ zl) {
    const int bm = blockIdx.x >> 2, bn = blockIdx.x & 3;
    const int m0 = bm * 128, n0 = bn * 128;
    __shared__ __align__(16) u16 Ah[128 * 64], Al[128 * 64];
    __shared__ __align__(16) u16 Bh[128 * 64], Bl[128 * 64];
    const int tid = threadIdx.x, lane = tid & 63, w = tid >> 6;
    const int rg = w >> 2, cg = w & 3;
    const int frow = lane & 15, fk = (lane >> 4) * 8;
    f32x4 acc[4][2] = {};

    for (int k0 = 0; k0 < 512; k0 += 64) {
        #pragma unroll
        for (int i = 0; i < 2; ++i) {
            int idx = i * 512 + tid;          // 1024 chunks per array
            int r = idx >> 3, c = idx & 7;
            int sc = (c ^ (r & 7)) * 8;
            gl_lds16(xh + (size_t)(m0 + r) * 512 + k0 + sc, &Ah[idx * 8]);
            gl_lds16(xl + (size_t)(m0 + r) * 512 + k0 + sc, &Al[idx * 8]);
            gl_lds16(Mth + (size_t)(n0 + r) * 512 + k0 + sc, &Bh[idx * 8]);
            gl_lds16(Mtl + (size_t)(n0 + r) * 512 + k0 + sc, &Bl[idx * 8]);
        }
        __syncthreads();
        #pragma unroll
        for (int kk = 0; kk < 2; ++kk) {
            s16x8 aH[4], aL[4], bH[2], bL[2];
            #pragma unroll
            for (int mi = 0; mi < 4; ++mi) {
                int row = rg * 64 + mi * 16 + frow;
                aH[mi] = *(const s16x8*)&Ah[swz(row, kk * 32 + fk)];
                aL[mi] = *(const s16x8*)&Al[swz(row, kk * 32 + fk)];
            }
            #pragma unroll
            for (int ni = 0; ni < 2; ++ni) {
                int row = cg * 32 + ni * 16 + frow;
                bH[ni] = *(const s16x8*)&Bh[swz(row, kk * 32 + fk)];
                bL[ni] = *(const s16x8*)&Bl[swz(row, kk * 32 + fk)];
            }
            #pragma unroll
            for (int mi = 0; mi < 4; ++mi)
                #pragma unroll
                for (int ni = 0; ni < 2; ++ni) {
                    acc[mi][ni] = __builtin_amdgcn_mfma_f32_16x16x32_bf16(aH[mi], bH[ni], acc[mi][ni], 0, 0, 0);
                    acc[mi][ni] = __builtin_amdgcn_mfma_f32_16x16x32_bf16(aH[mi], bL[ni], acc[mi][ni], 0, 0, 0);
                    acc[mi][ni] = __builtin_amdgcn_mfma_f32_16x16x32_bf16(aL[mi], bH[ni], acc[mi][ni], 0, 0, 0);
                }
        }
        __syncthreads();
    }
    #pragma unroll
    for (int ni = 0; ni < 2; ++ni) {
        int col = n0 + cg * 32 + ni * 16 + frow;
        float uv = u[col];
        #pragma unroll
        for (int mi = 0; mi < 4; ++mi) {
            int rbase = m0 + rg * 64 + mi * 16 + (lane >> 4) * 4;
            #pragma unroll
            for (int e = 0; e < 4; ++e) {
                float v = acc[mi][ni][e] + uv;
                u16 hi = f2bf(v);
                zh[(size_t)(rbase + e) * 512 + col] = hi;
                zl[(size_t)(rbase + e) * 512 + col] = f2bf(v - bf2f(hi));
            }
        }
    }
}

// ---------------- K5: banded scores S = z @ x^T, softmax -> P bf16 ----------------
// grid 256 = 4b x 64 row-tiles. block 512 (8 waves: 4 row-groups x 2 window-halves).
__global__ __launch_bounds__(512) void score_kernel(
    const u16* __restrict__ zh, const u16* __restrict__ zl,
    const u16* __restrict__ xh, const u16* __restrict__ xl,
    u16* __restrict__ P) {
    const int bid = blockIdx.x;
    const int b = bid >> 6, it = bid & 63;
    const int i0 = it * 64, j0 = i0 - 128;
    const int mrow0 = b * S_LEN + i0;
    __shared__ __align__(16) u16 Qh[64 * 64], Ql[64 * 64];
    __shared__ __align__(16) u16 Kh[320 * 64], Kl[320 * 64];
    __shared__ float smax[64][2], ssum[64][2];

    const int tid = threadIdx.x, lane = tid & 63, w = tid >> 6;
    const int g = w >> 1, half = w & 1;
    const int frow = lane & 15, fk = (lane >> 4) * 8;
    const int tstart = g + (half ? 9 : 0);
    const int nt = half ? 8 : 9;

    f32x4 acc[9] = {};

    for (int k0 = 0; k0 < 512; k0 += 64) {
        {
            int idx = tid;                       // 512 chunks per Q array
            int r = idx >> 3, c = idx & 7;
            int sc = (c ^ (r & 7)) * 8;
            gl_lds16(zh + (size_t)(mrow0 + r) * 512 + k0 + sc, &Qh[idx * 8]);
            gl_lds16(zl + (size_t)(mrow0 + r) * 512 + k0 + sc, &Ql[idx * 8]);
        }
        #pragma unroll
        for (int i = 0; i < 5; ++i) {
            int idx = i * 512 + tid;             // 2560 chunks per K array
            int r = idx >> 3, c = idx & 7;
            int sc = (c ^ (r & 7)) * 8;
            int j = j0 + r;
            int jc = min(max(j, 0), S_LEN - 1);
            gl_lds16(xh + (size_t)(b * S_LEN + jc) * 512 + k0 + sc, &Kh[idx * 8]);
            gl_lds16(xl + (size_t)(b * S_LEN + jc) * 512 + k0 + sc, &Kl[idx * 8]);
        }
        __syncthreads();
        #pragma unroll
        for (int kk = 0; kk < 2; ++kk) {
            int qrow = g * 16 + frow;
            s16x8 aH = *(const s16x8*)&Qh[swz(qrow, kk * 32 + fk)];
            s16x8 aL = *(const s16x8*)&Ql[swz(qrow, kk * 32 + fk)];
            #pragma unroll
            for (int tt = 0; tt < 9; ++tt) {
                if (tt < nt) {
                    int krow = (tstart + tt) * 16 + frow;
                    s16x8 bH = *(const s16x8*)&Kh[swz(krow, kk * 32 + fk)];
                    s16x8 bL = *(const s16x8*)&Kl[swz(krow, kk * 32 + fk)];
                    acc[tt] = __builtin_amdgcn_mfma_f32_16x16x32_bf16(aH, bH, acc[tt], 0, 0, 0);
                    acc[tt] = __builtin_amdgcn_mfma_f32_16x16x32_bf16(aH, bL, acc[tt], 0, 0, 0);
                    acc[tt] = __builtin_amdgcn_mfma_f32_16x16x32_bf16(aL, bH, acc[tt], 0, 0, 0);
                }
            }
        }
        __syncthreads();
    }

    const int rq = (lane >> 4) * 4;
    float mxh[4];
    #pragma unroll
    for (int e = 0; e < 4; ++e) {
        int r = g * 16 + rq + e;
        float m = NEG_INF_F;
        #pragma unroll
        for (int tt = 0; tt < 9; ++tt) {
            if (tt < nt) {
                int jj = (tstart + tt) * 16 + frow;
                int dj = jj - r, j = j0 + jj;
                if (dj >= 1 && dj <= 255 && j >= 0 && j < S_LEN) m = fmaxf(m, acc[tt][e]);
            }
        }
        #pragma unroll
        for (int d = 1; d < 16; d <<= 1) m = fmaxf(m, __shfl_xor(m, d));
        mxh[e] = m;
    }
    if (frow == 0) {
        #pragma unroll
        for (int e = 0; e < 4; ++e) smax[g * 16 + rq + e][half] = mxh[e];
    }
    __syncthreads();
    float p[9][4];
    float sh[4];
    #pragma unroll
    for (int e = 0; e < 4; ++e) {
        int r = g * 16 + rq + e;
        float mx = fmaxf(smax[r][0], smax[r][1]);
        float s = 0.f;
        #pragma unroll
        for (int tt = 0; tt < 9; ++tt) {
            float pv = 0.f;
            if (tt < nt) {
                int jj = (tstart + tt) * 16 + frow;
                int dj = jj - r, j = j0 + jj;
                bool valid = (dj >= 1 && dj <= 255 && j >= 0 && j < S_LEN);
                pv = valid ? __expf(acc[tt][e] - mx) : 0.f;
            }
            p[tt][e] = pv;
            s += pv;
        }
        #pragma unroll
        for (int d = 1; d < 16; d <<= 1) s += __shfl_xor(s, d);
        sh[e] = s;
    }
    if (frow == 0) {
        #pragma unroll
        for (int e = 0; e < 4; ++e) ssum[g * 16 + rq + e][half] = sh[e];
    }
    __syncthreads();
    float invv[4];
    #pragma unroll
    for (int e = 0; e < 4; ++e) {
        int r = g * 16 + rq + e;
        invv[e] = 1.f / (ssum[r][0] + ssum[r][1]);
    }
    #pragma unroll
    for (int tt = 0; tt < 9; ++tt) {
        if (tt < nt) {
            int t = tstart + tt;
            #pragma unroll
            for (int e = 0; e < 4; ++e) {
                int r = g * 16 + rq + e;
                P[(size_t)(mrow0 + r) * 320 + t * 16 + frow] = f2bf(p[tt][e] * invv[e]);
            }
        }
    }
    if (half == 0) {
        for (int t = 0; t < g; ++t)
            #pragma unroll
            for (int e = 0; e < 4; ++e)
                P[(size_t)(mrow0 + g * 16 + rq + e) * 320 + t * 16 + frow] = 0;
    } else {
        for (int t = g + 17; t < 20; ++t)
            #pragma unroll
            for (int e = 0; e < 4; ++e)
                P[(size_t)(mrow0 + g * 16 + rq + e) * 320 + t * 16 + frow] = 0;
    }
}

// ---------------- K6: out = P @ x_window (uses xT) ----------------
// grid 256 = 4b x 64 row-tiles. block 512 (8 waves: 2 row-groups x 4 d-blocks).
__global__ __launch_bounds__(512) void pv_kernel(
    const u16* __restrict__ P, const u16* __restrict__ xT,
    float* __restrict__ out) {
    const int bid = blockIdx.x;
    const int b = bid >> 6, it = bid & 63;
    const int i0 = it * 64, j0 = i0 - 128;
    const int mrow0 = b * S_LEN + i0;
    __shared__ __align__(16) u16 Ph[64 * 64];    // 8 KB
    __shared__ __align__(16) u16 XT[512 * 64];   // 64 KB
    const int tid = threadIdx.x, lane = tid & 63, w = tid >> 6;
    const int rg = w >> 2, dblk = w & 3;
    const int frow = lane & 15, fk = (lane >> 4) * 8;
    f32x4 acc[2][8] = {};

    for (int k0 = 0; k0 < 320; k0 += 64) {
        {
            int idx = tid;                       // 512 chunks (64 rows x 8)
            int r = idx >> 3, c = idx & 7;
            gl_lds16(P + (size_t)(mrow0 + r) * 320 + k0 + (c ^ (r & 7)) * 8, &Ph[idx * 8]);
        }
        #pragma unroll
        for (int i = 0; i < 8; ++i) {
            int idx = i * 512 + tid;             // 4096 chunks (512 d-rows x 8)
            int d = idx >> 3, c = idx & 7;
            int jb = j0 + k0 + (c ^ (d & 7)) * 8;
            jb = min(max(jb, 0), S_LEN - 8);     // clamped edges: P==0 there
            gl_lds16(xT + (size_t)(b * 512 + d) * S_LEN + jb, &XT[idx * 8]);
        }
        __syncthreads();
        #pragma unroll
        for (int kk = 0; kk < 2; ++kk) {
            s16x8 a[2];
            #pragma unroll
            for (int mi = 0; mi < 2; ++mi) {
                int row = rg * 32 + mi * 16 + frow;
                a[mi] = *(const s16x8*)&Ph[swz(row, kk * 32 + fk)];
            }
            #pragma unroll
            for (int ni = 0; ni < 8; ++ni) {
                int drow = dblk * 128 + ni * 16 + frow;
                s16x8 bf = *(const s16x8*)&XT[swz(drow, kk * 32 + fk)];
                acc[0][ni] = __builtin_amdgcn_mfma_f32_16x16x32_bf16(a[0], bf, acc[0][ni], 0, 0, 0);
                acc[1][ni] = __builtin_amdgcn_mfma_f32_16x16x32_bf16(a[1], bf, acc[1][ni], 0, 0, 0);
            }
        }
        __syncthreads();
    }
    #pragma unroll
    for (int mi = 0; mi < 2; ++mi) {
        #pragma unroll
        for (int ni = 0; ni < 8; ++ni) {
            int cidx = dblk * 128 + ni * 16 + frow;
            #pragma unroll
            for (int e = 0; e < 4; ++e) {
                int r = mrow0 + rg * 32 + mi * 16 + (lane >> 4) * 4 + e;
                out[(size_t)r * 512 + cidx] = acc[mi][ni][e];
            }
        }
    }
}

extern "C" void kernel_launch(void* const* d_in, const int* in_sizes, int n_in,
                              void* d_out, int out_size, void* d_ws, size_t ws_size,
                              hipStream_t stream) {
    const float* x  = (const float*)d_in[0];
    const float* Wq = (const float*)d_in[1];
    const float* bq = (const float*)d_in[2];
    const float* Wk = (const float*)d_in[3];
    const float* bk = (const float*)d_in[4];
    (void)bk;
    float* out = (float*)d_out;

    u16* xh  = (u16*)d_ws;
    u16* xl  = xh + (size_t)8388608;
    u16* zh  = xl + (size_t)8388608;
    u16* zl  = zh + (size_t)8388608;
    u16* Mth = zl + (size_t)8388608;
    u16* Mtl = Mth + (size_t)262144;
    u16* Pb  = Mtl + (size_t)262144;
    float* uv = (float*)(Pb + (size_t)16384 * 320);
    u16* xT  = zh;   // alias: zh/zl dead after score_kernel, xT written after

    hipLaunchKernelGGL(split_kernel, dim3(2048), dim3(256), 0, stream, x, xh, xl);
    hipLaunchKernelGGL(mt_kernel, dim3(64), dim3(256), 0, stream, Wk, Wq, Mth, Mtl);
    hipLaunchKernelGGL(u_kernel, dim3(8), dim3(256), 0, stream, Wk, bq, uv);
    hipLaunchKernelGGL(z_kernel, dim3(512), dim3(512), 0, stream,
                       xh, xl, Mth, Mtl, uv, zh, zl);
    hipLaunchKernelGGL(score_kernel, dim3(256), dim3(512), 0, stream,
                       zh, zl, xh, xl, Pb);
    hipLaunchKernelGGL(xt_kernel, dim3(2048), dim3(256), 0, stream, xh, xT);
    hipLaunchKernelGGL(pv_kernel, dim3(256), dim3(512), 0, stream, Pb, xT, out);
}